// Round 1
// baseline (4586.676 us; speedup 1.0000x reference)
//
#include <hip/hip_runtime.h>
#include <hip/hip_bf16.h>

#define HWD 188
#define NB 4
#define CIN 512
#define CH 64
#define MBOX 200
#define NMAX 500

// output offsets (in floats)
#define HEAD_SZ (NB*12*HWD*HWD)
#define HM_OFF  HEAD_SZ
#define TB_OFF  (HM_OFF + NB*3*HWD*HWD)
#define IND_OFF (TB_OFF + NB*NMAX*8)
#define MSK_OFF (IND_OFF + NB*NMAX)

__device__ __forceinline__ float to_f(float v) { return v; }
__device__ __forceinline__ float to_f(__hip_bfloat16 v) { return __bfloat162float(v); }

__device__ __forceinline__ unsigned short bf16_bits(float v) {
  __hip_bfloat16 h = __float2bfloat16(v);
  union { __hip_bfloat16 h; unsigned short u; } cv; cv.h = h; return cv.u;
}

// ---------------- weight pre-transform ----------------
// wT  [512][9][64]  <- w_shared [64][512][3][3]
// w1T [6][64][9][64] <- w1_heads [6][64][64][3][3]
// w2T [6][64][9][3]  <- w2_heads [6][3][64][3][3]
__global__ __launch_bounds__(256) void transform_weights(
    const float* __restrict__ ws_, const float* __restrict__ w1_,
    const float* __restrict__ w2_, float* __restrict__ wT,
    float* __restrict__ w1T, float* __restrict__ w2T) {
  int e = blockIdx.x * 256 + threadIdx.x;
  const int N0 = CIN * 9 * CH;     // 294912
  const int N1 = 6 * CH * 9 * CH;  // 221184
  const int N2 = 6 * CH * 9 * 3;   // 10368
  if (e < N0) {
    int ic = e / (9 * CH); int rem = e - ic * 9 * CH;
    int tap = rem / CH; int oc = rem - tap * CH;
    wT[e] = ws_[(oc * CIN + ic) * 9 + tap];
  } else if (e < N0 + N1) {
    int f = e - N0;
    int h = f / (CH * 9 * CH); int r = f - h * CH * 9 * CH;
    int ic = r / (9 * CH); int r2 = r - ic * 9 * CH;
    int tap = r2 / CH; int oc = r2 - tap * CH;
    w1T[f] = w1_[((h * CH + oc) * CH + ic) * 9 + tap];
  } else if (e < N0 + N1 + N2) {
    int f = e - N0 - N1;
    int h = f / (CH * 27); int r = f - h * CH * 27;
    int ic = r / 27; int r2 = r - ic * 27;
    int tap = r2 / 3; int oc = r2 - tap * 3;
    w2T[f] = w2_[((h * 3 + oc) * CH + ic) * 9 + tap];
  }
}

// ---------------- conv 3x3 -> BN -> ReLU -> bf16 ----------------
// block: 256 threads = 4 oc-groups x 64 px-threads; each thread 4px x 16oc.
// tile: 32(x) x 8(y) px, 64 oc. grid: (144, B)
template<int IC, typename TIn>
__global__ __launch_bounds__(256) void conv_bnrelu(
    const TIn* __restrict__ in,            // [B][IC][HWD][HWD]
    const float* __restrict__ wT,          // [IC][9][64]
    const float* __restrict__ bn,          // [4][64]
    __hip_bfloat16* __restrict__ out) {    // [B][64][HWD][HWD]
  constexpr int ICB = 4;
  __shared__ __align__(16) float s_in[ICB][10][37];
  __shared__ __align__(16) float s_w[ICB][9][CH];
  const int t = threadIdx.x;
  const int b = blockIdx.y;
  const int tile = blockIdx.x;
  const int ty0 = (tile / 6) * 8, tx0 = (tile % 6) * 32;
  const int oc_t = t >> 6;            // 0..3
  const int px = t & 63;
  const int yl = px >> 3, xl = (px & 7) * 4;

  float acc[4][16];
#pragma unroll
  for (int p = 0; p < 4; ++p)
#pragma unroll
    for (int o = 0; o < 16; ++o) acc[p][o] = 0.f;

  for (int ic0 = 0; ic0 < IC; ic0 += ICB) {
    __syncthreads();
    for (int e = t; e < ICB * 10 * 34; e += 256) {
      int ii = e / 340; int rem = e - ii * 340;
      int row = rem / 34; int col = rem - row * 34;
      int gy = ty0 + row - 1, gx = tx0 + col - 1;
      float v = 0.f;
      if (gy >= 0 && gy < HWD && gx >= 0 && gx < HWD)
        v = to_f(in[(((long long)b * IC + ic0 + ii) * HWD + gy) * HWD + gx]);
      s_in[ii][row][col] = v;
    }
    const float* wsrc = wT + (long long)ic0 * 9 * CH;
    for (int e = t; e < ICB * 9 * CH; e += 256) ((float*)s_w)[e] = wsrc[e];
    __syncthreads();
#pragma unroll
    for (int i = 0; i < ICB; ++i) {
#pragma unroll
      for (int ky = 0; ky < 3; ++ky) {
        float win[6];
#pragma unroll
        for (int c = 0; c < 6; ++c) win[c] = s_in[i][yl + ky][xl + c];
#pragma unroll
        for (int kx = 0; kx < 3; ++kx) {
          const float* wp = &s_w[i][ky * 3 + kx][oc_t * 16];
#pragma unroll
          for (int o = 0; o < 16; ++o) {
            float wv = wp[o];
#pragma unroll
            for (int p = 0; p < 4; ++p) acc[p][o] = fmaf(win[kx + p], wv, acc[p][o]);
          }
        }
      }
    }
  }
  // epilogue: BN + ReLU + bf16 store
  const int gy = ty0 + yl;
  if (gy >= HWD) return;
  const int gx0 = tx0 + xl;
  const bool full = (gx0 + 3 < HWD);
#pragma unroll
  for (int o = 0; o < 16; ++o) {
    int c = oc_t * 16 + o;
    float g = bn[c], be = bn[64 + c], m = bn[128 + c], v = bn[192 + c];
    float scale = g * rsqrtf(v + 1e-5f);
    float bias = be - m * scale;
    long long base = (((long long)b * CH + c) * HWD + gy) * HWD;
    float r0 = fmaxf(acc[0][o] * scale + bias, 0.f);
    float r1 = fmaxf(acc[1][o] * scale + bias, 0.f);
    float r2 = fmaxf(acc[2][o] * scale + bias, 0.f);
    float r3 = fmaxf(acc[3][o] * scale + bias, 0.f);
    if (full) {
      ushort4 pk;
      pk.x = bf16_bits(r0); pk.y = bf16_bits(r1);
      pk.z = bf16_bits(r2); pk.w = bf16_bits(r3);
      *reinterpret_cast<ushort4*>(&out[base + gx0]) = pk;
    } else {
      float rr[4] = {r0, r1, r2, r3};
      for (int p = 0; p < 4; ++p) {
        int gx = gx0 + p;
        if (gx < HWD) out[base + gx] = __float2bfloat16(rr[p]);
      }
    }
  }
}

// ---------------- conv3: 64 -> 3 + bias, write selected channels ----------------
__global__ __launch_bounds__(256) void conv3_head(
    const __hip_bfloat16* __restrict__ in,  // tmp [B][64][HWD][HWD]
    const float* __restrict__ w2T,          // [6][64][9][3]
    const float* __restrict__ b2,           // [6][3]
    float* __restrict__ head_out,           // [B][12][HWD][HWD]
    int h, int c_off, int noc) {
  constexpr int ICB = 8;
  __shared__ float s_in[ICB][10][37];
  __shared__ float s_w[ICB][9][3];
  const int t = threadIdx.x, b = blockIdx.y, tile = blockIdx.x;
  const int ty0 = (tile / 6) * 8, tx0 = (tile % 6) * 32;
  const int yl = t >> 5, xl = t & 31;
  float acc[3] = {0.f, 0.f, 0.f};
  for (int ic0 = 0; ic0 < CH; ic0 += ICB) {
    __syncthreads();
    for (int e = t; e < ICB * 10 * 34; e += 256) {
      int ii = e / 340; int rem = e - ii * 340;
      int row = rem / 34; int col = rem - row * 34;
      int gy = ty0 + row - 1, gx = tx0 + col - 1;
      float v = 0.f;
      if (gy >= 0 && gy < HWD && gx >= 0 && gx < HWD)
        v = __bfloat162float(in[(((long long)b * CH + ic0 + ii) * HWD + gy) * HWD + gx]);
      s_in[ii][row][col] = v;
    }
    for (int e = t; e < ICB * 27; e += 256)
      ((float*)s_w)[e] = w2T[h * (CH * 27) + ic0 * 27 + e];
    __syncthreads();
#pragma unroll
    for (int i = 0; i < ICB; ++i) {
#pragma unroll
      for (int ky = 0; ky < 3; ++ky) {
        float wn[3];
#pragma unroll
        for (int c = 0; c < 3; ++c) wn[c] = s_in[i][yl + ky][xl + c];
#pragma unroll
        for (int kx = 0; kx < 3; ++kx) {
#pragma unroll
          for (int o = 0; o < 3; ++o)
            acc[o] = fmaf(wn[kx], s_w[i][ky * 3 + kx][o], acc[o]);
        }
      }
    }
  }
  const int gy = ty0 + yl, gx = tx0 + xl;
  if (gy < HWD && gx < HWD) {
    for (int o = 0; o < noc; ++o)
      head_out[(((long long)b * 12 + c_off + o) * HWD + gy) * HWD + gx] =
          acc[o] + b2[h * 3 + o];
  }
}

// ---------------- assign_targets: per-box ----------------
__global__ __launch_bounds__(256) void targets_kernel(
    const float* __restrict__ gt, float* __restrict__ out, float* __restrict__ boxp) {
  int idx = blockIdx.x * 256 + threadIdx.x;
  if (idx >= NB * NMAX) return;
  int b = idx / NMAX, j = idx - b * NMAX;
  float vals[8] = {0, 0, 0, 0, 0, 0, 0, 0};
  float indf = 0.f, mkf = 0.f;
  if (j < MBOX) {
    const float* g = gt + ((long long)b * MBOX + j) * 8;
    float x = g[0], y = g[1], z = g[2], dx = g[3], dy = g[4], dz = g[5];
    float hd = g[6], cls = g[7];
    float cx = (x - (-75.2f)) / 0.1f / 8.0f;
    cx = fminf(fmaxf(cx, 0.0f), (float)HWD - 0.5f);
    float cy = (y - (-75.2f)) / 0.1f / 8.0f;
    cy = fminf(fmaxf(cy, 0.0f), (float)HWD - 0.5f);
    float cxf = floorf(cx), cyf = floorf(cy);
    int cxi = (int)cxf, cyi = (int)cyf;
    float hh = dx / 0.1f / 8.0f;   // height = dxp
    float ww = dy / 0.1f / 8.0f;   // width  = dyp
    const float ov = 0.1f;
    float b1 = hh + ww;
    float c1 = ww * hh * (1.0f - ov) / (1.0f + ov);
    float sq1 = sqrtf(fmaxf(b1 * b1 - 4.0f * c1, 0.0f));
    float r1 = (b1 + sq1) / 2.0f;
    float b2_ = 2.0f * (hh + ww);
    float c2 = (1.0f - ov) * ww * hh;
    float sq2 = sqrtf(fmaxf(b2_ * b2_ - 16.0f * c2, 0.0f));
    float r2 = (b2_ + sq2) / 2.0f;
    float a3 = 4.0f * ov;
    float b3 = -2.0f * ov * (hh + ww);
    float c3 = (ov - 1.0f) * ww * hh;
    float sq3 = sqrtf(fmaxf(b3 * b3 - 4.0f * a3 * c3, 0.0f));
    float r3 = (b3 + sq3) / 2.0f;
    float r = fminf(fminf(r1, r2), r3);
    r = fmaxf(floorf(r), 2.0f);
    float sigma = (2.0f * r + 1.0f) / 6.0f;
    float inv2s2 = 1.0f / (2.0f * sigma * sigma);
    bool valid = (dx > 0.0f) && (dy > 0.0f);
    float vf = valid ? 1.0f : 0.0f;
    vals[0] = (cx - cxf) * vf;
    vals[1] = (cy - cyf) * vf;
    vals[2] = z * vf;
    vals[3] = logf(dx) * vf;
    vals[4] = logf(dy) * vf;
    vals[5] = logf(dz) * vf;
    vals[6] = cosf(hd) * vf;
    vals[7] = sinf(hd) * vf;
    indf = (float)((cyi * HWD + cxi) * (valid ? 1 : 0));
    mkf = vf;
    float* bp = boxp + ((long long)b * MBOX + j) * 8;
    bp[0] = cxf; bp[1] = cyf; bp[2] = r; bp[3] = inv2s2;
    bp[4] = valid ? cls : 0.0f; bp[5] = 0.f; bp[6] = 0.f; bp[7] = 0.f;
  }
  float* tb = out + TB_OFF + ((long long)b * NMAX + j) * 8;
#pragma unroll
  for (int k = 0; k < 8; ++k) tb[k] = vals[k];
  out[IND_OFF + b * NMAX + j] = indf;
  out[MSK_OFF + b * NMAX + j] = mkf;
}

// ---------------- heatmap: per-pixel max over boxes ----------------
__global__ __launch_bounds__(256) void heatmap_kernel(
    const float* __restrict__ boxp, float* __restrict__ out) {
  __shared__ float s_bp[MBOX][5];
  const int t = threadIdx.x, b = blockIdx.y;
  for (int e = t; e < MBOX * 5; e += 256) {
    int j = e / 5, k = e - j * 5;
    s_bp[j][k] = boxp[((long long)b * MBOX + j) * 8 + k];
  }
  __syncthreads();
  int p = blockIdx.x * 256 + t;
  if (p >= HWD * HWD) return;
  int y = p / HWD, x = p - y * HWD;
  float a0 = 0.f, a1 = 0.f, a2 = 0.f;
  for (int j = 0; j < MBOX; ++j) {
    int c = (int)s_bp[j][4];
    if (c == 0) continue;
    float ox = (float)x - s_bp[j][0];
    float oy = (float)y - s_bp[j][1];
    float r = s_bp[j][2];
    if (fabsf(ox) <= r && fabsf(oy) <= r) {
      float gg = expf(-(ox * ox + oy * oy) * s_bp[j][3]);
      if (c == 1) a0 = fmaxf(a0, gg);
      else if (c == 2) a1 = fmaxf(a1, gg);
      else a2 = fmaxf(a2, gg);
    }
  }
  long long base = HM_OFF + ((long long)b * 3 * HWD + y) * HWD + x;
  out[base] = a0;
  out[base + (long long)HWD * HWD] = a1;
  out[base + 2LL * HWD * HWD] = a2;
}

extern "C" void kernel_launch(void* const* d_in, const int* in_sizes, int n_in,
                              void* d_out, int out_size, void* d_ws, size_t ws_size,
                              hipStream_t stream) {
  (void)in_sizes; (void)n_in; (void)out_size; (void)ws_size;
  const float* sf = (const float*)d_in[0];
  const float* gt = (const float*)d_in[1];
  const float* w_shared = (const float*)d_in[2];
  const float* bn_shared = (const float*)d_in[3];
  const float* w1 = (const float*)d_in[4];
  const float* bnH = (const float*)d_in[5];
  const float* w2 = (const float*)d_in[6];
  const float* b2 = (const float*)d_in[7];
  float* out = (float*)d_out;
  char* ws = (char*)d_ws;

  const size_t SH_BYTES = (size_t)NB * CH * HWD * HWD * 2;  // 18,096,128
  __hip_bfloat16* shared = (__hip_bfloat16*)ws;
  __hip_bfloat16* tmp = (__hip_bfloat16*)(ws + SH_BYTES);
  float* wT = (float*)(ws + 2 * SH_BYTES);
  float* w1T = wT + (size_t)CIN * 9 * CH;
  float* w2T = w1T + (size_t)6 * CH * 9 * CH;
  float* boxp = w2T + (size_t)6 * CH * 9 * 3;

  const int NW = CIN * 9 * CH + 6 * CH * 9 * CH + 6 * CH * 9 * 3;  // 526464
  transform_weights<<<(NW + 255) / 256, 256, 0, stream>>>(w_shared, w1, w2, wT, w1T, w2T);

  dim3 cgrid(144, NB);
  conv_bnrelu<CIN, float><<<cgrid, 256, 0, stream>>>(sf, wT, bn_shared, shared);

  const int cum[6] = {0, 2, 3, 6, 8, 9};
  const int outc[6] = {2, 1, 3, 2, 1, 3};
  for (int h = 0; h < 6; ++h) {
    conv_bnrelu<CH, __hip_bfloat16><<<cgrid, 256, 0, stream>>>(
        shared, w1T + (size_t)h * CH * 9 * CH, bnH + h * 256, tmp);
    conv3_head<<<cgrid, 256, 0, stream>>>(tmp, w2T, b2, out, h, cum[h], outc[h]);
  }

  targets_kernel<<<(NB * NMAX + 255) / 256, 256, 0, stream>>>(gt, out, boxp);
  dim3 hgrid((HWD * HWD + 255) / 256, NB);
  heatmap_kernel<<<hgrid, 256, 0, stream>>>(boxp, out);
}

// Round 2
// 664.649 us; speedup vs baseline: 6.9009x; 6.9009x over previous
//
#include <hip/hip_runtime.h>
#include <hip/hip_bf16.h>

#define HWD 188
#define NPX (HWD*HWD)
#define NB 4
#define CIN 512
#define CH 64
#define MBOX 200
#define NMAX 500

// output offsets (floats)
#define HEAD_SZ (NB*12*NPX)
#define HM_OFF  HEAD_SZ
#define TB_OFF  (HM_OFF + NB*3*NPX)
#define IND_OFF (TB_OFF + NB*NMAX*8)
#define MSK_OFF (IND_OFF + NB*NMAX)

typedef short sh8 __attribute__((ext_vector_type(8)));
typedef float f4 __attribute__((ext_vector_type(4)));
typedef unsigned short us4 __attribute__((ext_vector_type(4)));

__device__ __constant__ int d_cum[6]  = {0, 2, 3, 6, 8, 9};
__device__ __constant__ int d_outc[6] = {2, 1, 3, 2, 1, 3};

__device__ __forceinline__ unsigned short bf16_bits(float v) {
  union { __hip_bfloat16 h; unsigned short u; } cv;
  cv.h = __float2bfloat16(v);
  return cv.u;
}

// ---------------- weight pre-transform to bf16 MFMA layouts ----------------
// w1b [9][64][512]  <- w_shared [64][512][3][3]
// w2b [6][9][64][64] <- w1_heads [6][64][64][3][3]
// w3b [6][9][16][64] <- w2_heads [6][3][64][3][3]  (oc padded 3->16 with 0)
__global__ __launch_bounds__(256) void wprep(
    const float* __restrict__ ws_, const float* __restrict__ w1_,
    const float* __restrict__ w2_, unsigned short* __restrict__ w1b,
    unsigned short* __restrict__ w2b, unsigned short* __restrict__ w3b) {
  int e = blockIdx.x * 256 + threadIdx.x;
  const int N1 = 9 * 64 * 512;
  const int N2 = 6 * 9 * 64 * 64;
  const int N3 = 6 * 9 * 16 * 64;
  if (e < N1) {
    int tap = e / (64 * 512); int r = e % (64 * 512);
    int oc = r / 512; int ic = r % 512;
    w1b[e] = bf16_bits(ws_[(oc * 512 + ic) * 9 + tap]);
  } else if (e < N1 + N2) {
    int f = e - N1;
    int h = f / (9 * 64 * 64); int r = f % (9 * 64 * 64);
    int tap = r / (64 * 64); int r2 = r % (64 * 64);
    int oc = r2 / 64; int ic = r2 % 64;
    w2b[f] = bf16_bits(w1_[((h * 64 + oc) * 64 + ic) * 9 + tap]);
  } else if (e < N1 + N2 + N3) {
    int f = e - N1 - N2;
    int h = f / (9 * 16 * 64); int r = f % (9 * 16 * 64);
    int tap = r / (16 * 64); int r2 = r % (16 * 64);
    int oc = r2 / 64; int ic = r2 % 64;
    float v = (oc < 3) ? w2_[((h * 3 + oc) * 64 + ic) * 9 + tap] : 0.f;
    w3b[f] = bf16_bits(v);
  }
}

// ---------------- conv1: 512->64 MFMA, BN+ReLU -> bf16 NHWC ----------------
// block 256 = 4 waves. tile 8r x 32c x 64oc. wave: 4 oc-tiles x 4 n-tiles.
// LDS [10][34][32ic] bf16, ic-innermost (B-frag ds_read_b128 is wave-linear).
__global__ __launch_bounds__(256) void conv1_mfma(
    const float* __restrict__ sf,           // [B][512][188][188] f32
    const unsigned short* __restrict__ wb,  // [9][64][512] bf16
    const float* __restrict__ bnp,          // [4][64]
    unsigned short* __restrict__ outp) {    // NHWC [B][188][188][64] bf16
  __shared__ __align__(16) short s_in[10 * 34 * 32];
  const int t = threadIdx.x;
  const int b = blockIdx.y;
  const int rt = blockIdx.x / 6, ct = blockIdx.x % 6;
  const int y0 = rt * 8, x0 = ct * 32;
  const int w = t >> 6, lane = t & 63, ln = lane & 15, kg = lane >> 4;

  f4 acc[4][4];
#pragma unroll
  for (int i = 0; i < 4; ++i)
#pragma unroll
    for (int j = 0; j < 4; ++j) acc[i][j] = (f4){0.f, 0.f, 0.f, 0.f};

  for (int ic0 = 0; ic0 < CIN; ic0 += 32) {
    __syncthreads();
    // stage 10r x 34c x 32ic (zero-padded borders), 4-ic packs
    for (int idx = t; idx < 2720; idx += 256) {
      int c = idx % 34; int rem = idx / 34;
      int r = rem % 10; int iq = rem / 10;
      int gy = y0 - 1 + r, gx = x0 - 1 + c;
      float v0 = 0.f, v1 = 0.f, v2 = 0.f, v3 = 0.f;
      if (gy >= 0 && gy < HWD && gx >= 0 && gx < HWD) {
        const float* p = sf + ((b * CIN + ic0 + iq * 4) * HWD + gy) * HWD + gx;
        v0 = p[0]; v1 = p[NPX]; v2 = p[2 * NPX]; v3 = p[3 * NPX];
      }
      us4 pk = {bf16_bits(v0), bf16_bits(v1), bf16_bits(v2), bf16_bits(v3)};
      *reinterpret_cast<us4*>(&s_in[(r * 34 + c) * 32 + iq * 4]) = pk;
    }
    __syncthreads();
    for (int tap = 0; tap < 9; ++tap) {
      const int ky = tap / 3, kx = tap % 3;
      sh8 af[4];
#pragma unroll
      for (int ot = 0; ot < 4; ++ot)
        af[ot] = *reinterpret_cast<const sh8*>(
            wb + (tap * 64 + ot * 16 + ln) * CIN + ic0 + kg * 8);
#pragma unroll
      for (int nt = 0; nt < 4; ++nt) {
        const int rr = 2 * w + (nt >> 1) + ky;
        const int cc = (nt & 1) * 16 + ln + kx;
        sh8 bf = *reinterpret_cast<const sh8*>(&s_in[(rr * 34 + cc) * 32 + kg * 8]);
#pragma unroll
        for (int ot = 0; ot < 4; ++ot)
          acc[ot][nt] = __builtin_amdgcn_mfma_f32_16x16x32_bf16(
              af[ot], bf, acc[ot][nt], 0, 0, 0);
      }
    }
  }
  // epilogue: BN + ReLU -> bf16 NHWC
#pragma unroll
  for (int ot = 0; ot < 4; ++ot) {
    const int ocb = ot * 16 + kg * 4;
    f4 g4 = *reinterpret_cast<const f4*>(bnp + ocb);
    f4 b4 = *reinterpret_cast<const f4*>(bnp + 64 + ocb);
    f4 m4 = *reinterpret_cast<const f4*>(bnp + 128 + ocb);
    f4 v4 = *reinterpret_cast<const f4*>(bnp + 192 + ocb);
    f4 sc, bi;
#pragma unroll
    for (int j = 0; j < 4; ++j) {
      sc[j] = g4[j] * rsqrtf(v4[j] + 1e-5f);
      bi[j] = b4[j] - m4[j] * sc[j];
    }
#pragma unroll
    for (int nt = 0; nt < 4; ++nt) {
      int y = y0 + 2 * w + (nt >> 1);
      int x = x0 + (nt & 1) * 16 + ln;
      if (y < HWD && x < HWD) {
        us4 pk;
#pragma unroll
        for (int j = 0; j < 4; ++j)
          pk[j] = bf16_bits(fmaxf(acc[ot][nt][j] * sc[j] + bi[j], 0.f));
        *reinterpret_cast<us4*>(outp + ((b * HWD + y) * HWD + x) * 64 + ocb) = pk;
      }
    }
  }
}

// ---------------- head convs (64->64 BN+ReLU | 64->16(3) +bias) ----------------
// EPI=0: conv2, out bf16 NHWC tmp.  EPI=1: conv3, out f32 NCHW head slices.
template<int OCT, int EPI>
__global__ __launch_bounds__(256) void conv_head_mfma(
    const unsigned short* __restrict__ inp,   // NHWC bf16 (EPI1: tmp base)
    const unsigned short* __restrict__ wb0,   // [6][9][OCT*16][64]
    const float* __restrict__ bn0,            // EPI0: [6][4][64]
    const float* __restrict__ b2,             // EPI1: [6][3]
    unsigned short* __restrict__ outp0,       // EPI0: tmp base
    float* __restrict__ hout,                 // EPI1: head_out
    int h_base, long long stride) {
  __shared__ __align__(16) short s_in[10 * 34 * 32];
  const int t = threadIdx.x;
  const int b = blockIdx.y;
  const int h = h_base + blockIdx.z;
  const int rt = blockIdx.x / 6, ct = blockIdx.x % 6;
  const int y0 = rt * 8, x0 = ct * 32;
  const int w = t >> 6, lane = t & 63, ln = lane & 15, kg = lane >> 4;

  const unsigned short* wb = wb0 + h * (9 * OCT * 16 * 64);
  const unsigned short* in_t = (EPI == 1) ? inp + h * stride : inp;

  f4 acc[OCT][4];
#pragma unroll
  for (int i = 0; i < OCT; ++i)
#pragma unroll
    for (int j = 0; j < 4; ++j) acc[i][j] = (f4){0.f, 0.f, 0.f, 0.f};

  for (int ic0 = 0; ic0 < CH; ic0 += 32) {
    __syncthreads();
    for (int idx = t; idx < 1360; idx += 256) {
      int icg = idx & 3; int pix = idx >> 2;
      int c = pix % 34; int r = pix / 34;
      int gy = y0 - 1 + r, gx = x0 - 1 + c;
      sh8 v = (sh8){0, 0, 0, 0, 0, 0, 0, 0};
      if (gy >= 0 && gy < HWD && gx >= 0 && gx < HWD)
        v = *reinterpret_cast<const sh8*>(
            &in_t[((b * HWD + gy) * HWD + gx) * 64 + ic0 + icg * 8]);
      *reinterpret_cast<sh8*>(&s_in[(r * 34 + c) * 32 + icg * 8]) = v;
    }
    __syncthreads();
    for (int tap = 0; tap < 9; ++tap) {
      const int ky = tap / 3, kx = tap % 3;
      sh8 af[OCT];
#pragma unroll
      for (int ot = 0; ot < OCT; ++ot)
        af[ot] = *reinterpret_cast<const sh8*>(
            wb + (tap * OCT * 16 + ot * 16 + ln) * 64 + ic0 + kg * 8);
#pragma unroll
      for (int nt = 0; nt < 4; ++nt) {
        const int rr = 2 * w + (nt >> 1) + ky;
        const int cc = (nt & 1) * 16 + ln + kx;
        sh8 bf = *reinterpret_cast<const sh8*>(&s_in[(rr * 34 + cc) * 32 + kg * 8]);
#pragma unroll
        for (int ot = 0; ot < OCT; ++ot)
          acc[ot][nt] = __builtin_amdgcn_mfma_f32_16x16x32_bf16(
              af[ot], bf, acc[ot][nt], 0, 0, 0);
      }
    }
  }
  if (EPI == 0) {
    unsigned short* outp = outp0 + h * stride;
#pragma unroll
    for (int ot = 0; ot < OCT; ++ot) {
      const int ocb = ot * 16 + kg * 4;
      const float* bnp = bn0 + h * 256;
      f4 g4 = *reinterpret_cast<const f4*>(bnp + ocb);
      f4 b4 = *reinterpret_cast<const f4*>(bnp + 64 + ocb);
      f4 m4 = *reinterpret_cast<const f4*>(bnp + 128 + ocb);
      f4 v4 = *reinterpret_cast<const f4*>(bnp + 192 + ocb);
      f4 sc, bi;
#pragma unroll
      for (int j = 0; j < 4; ++j) {
        sc[j] = g4[j] * rsqrtf(v4[j] + 1e-5f);
        bi[j] = b4[j] - m4[j] * sc[j];
      }
#pragma unroll
      for (int nt = 0; nt < 4; ++nt) {
        int y = y0 + 2 * w + (nt >> 1);
        int x = x0 + (nt & 1) * 16 + ln;
        if (y < HWD && x < HWD) {
          us4 pk;
#pragma unroll
          for (int j = 0; j < 4; ++j)
            pk[j] = bf16_bits(fmaxf(acc[ot][nt][j] * sc[j] + bi[j], 0.f));
          *reinterpret_cast<us4*>(outp + ((b * HWD + y) * HWD + x) * 64 + ocb) = pk;
        }
      }
    }
  } else {
    const int c_off = d_cum[h], noc = d_outc[h];
    const float* bias = b2 + h * 3;
#pragma unroll
    for (int nt = 0; nt < 4; ++nt) {
      int y = y0 + 2 * w + (nt >> 1);
      int x = x0 + (nt & 1) * 16 + ln;
      if (y < HWD && x < HWD) {
#pragma unroll
        for (int j = 0; j < 4; ++j) {
          int oc = kg * 4 + j;
          if (oc < noc)
            hout[(b * 12 + c_off + oc) * NPX + y * HWD + x] =
                acc[0][nt][j] + bias[oc];
        }
      }
    }
  }
}

// ---------------- assign_targets: per-box ----------------
__global__ __launch_bounds__(256) void targets_kernel(
    const float* __restrict__ gt, float* __restrict__ out, float* __restrict__ boxp) {
  int idx = blockIdx.x * 256 + threadIdx.x;
  if (idx >= NB * NMAX) return;
  int b = idx / NMAX, j = idx - b * NMAX;
  float vals[8] = {0, 0, 0, 0, 0, 0, 0, 0};
  float indf = 0.f, mkf = 0.f;
  if (j < MBOX) {
    const float* g = gt + (b * MBOX + j) * 8;
    float x = g[0], y = g[1], z = g[2], dx = g[3], dy = g[4], dz = g[5];
    float hd = g[6], cls = g[7];
    float cx = (x - (-75.2f)) / 0.1f / 8.0f;
    cx = fminf(fmaxf(cx, 0.0f), (float)HWD - 0.5f);
    float cy = (y - (-75.2f)) / 0.1f / 8.0f;
    cy = fminf(fmaxf(cy, 0.0f), (float)HWD - 0.5f);
    float cxf = floorf(cx), cyf = floorf(cy);
    int cxi = (int)cxf, cyi = (int)cyf;
    float hh = dx / 0.1f / 8.0f;
    float ww = dy / 0.1f / 8.0f;
    const float ov = 0.1f;
    float b1 = hh + ww;
    float c1 = ww * hh * (1.0f - ov) / (1.0f + ov);
    float sq1 = sqrtf(fmaxf(b1 * b1 - 4.0f * c1, 0.0f));
    float r1 = (b1 + sq1) / 2.0f;
    float b2_ = 2.0f * (hh + ww);
    float c2 = (1.0f - ov) * ww * hh;
    float sq2 = sqrtf(fmaxf(b2_ * b2_ - 16.0f * c2, 0.0f));
    float r2 = (b2_ + sq2) / 2.0f;
    float a3 = 4.0f * ov;
    float b3 = -2.0f * ov * (hh + ww);
    float c3 = (ov - 1.0f) * ww * hh;
    float sq3 = sqrtf(fmaxf(b3 * b3 - 4.0f * a3 * c3, 0.0f));
    float r3 = (b3 + sq3) / 2.0f;
    float r = fminf(fminf(r1, r2), r3);
    r = fmaxf(floorf(r), 2.0f);
    float sigma = (2.0f * r + 1.0f) / 6.0f;
    float inv2s2 = 1.0f / (2.0f * sigma * sigma);
    bool valid = (dx > 0.0f) && (dy > 0.0f);
    float vf = valid ? 1.0f : 0.0f;
    vals[0] = (cx - cxf) * vf;
    vals[1] = (cy - cyf) * vf;
    vals[2] = z * vf;
    vals[3] = logf(dx) * vf;
    vals[4] = logf(dy) * vf;
    vals[5] = logf(dz) * vf;
    vals[6] = cosf(hd) * vf;
    vals[7] = sinf(hd) * vf;
    indf = (float)((cyi * HWD + cxi) * (valid ? 1 : 0));
    mkf = vf;
    float* bp = boxp + (b * MBOX + j) * 8;
    bp[0] = cxf; bp[1] = cyf; bp[2] = r; bp[3] = inv2s2;
    bp[4] = valid ? cls : 0.0f; bp[5] = 0.f; bp[6] = 0.f; bp[7] = 0.f;
  }
  float* tb = out + TB_OFF + (b * NMAX + j) * 8;
#pragma unroll
  for (int k = 0; k < 8; ++k) tb[k] = vals[k];
  out[IND_OFF + b * NMAX + j] = indf;
  out[MSK_OFF + b * NMAX + j] = mkf;
}

// ---------------- heatmap: per-pixel max over boxes ----------------
__global__ __launch_bounds__(256) void heatmap_kernel(
    const float* __restrict__ boxp, float* __restrict__ out) {
  __shared__ float s_bp[MBOX][5];
  const int t = threadIdx.x, b = blockIdx.y;
  for (int e = t; e < MBOX * 5; e += 256) {
    int j = e / 5, k = e - j * 5;
    s_bp[j][k] = boxp[(b * MBOX + j) * 8 + k];
  }
  __syncthreads();
  int p = blockIdx.x * 256 + t;
  if (p >= NPX) return;
  int y = p / HWD, x = p - y * HWD;
  float a0 = 0.f, a1 = 0.f, a2 = 0.f;
  for (int j = 0; j < MBOX; ++j) {
    int c = (int)s_bp[j][4];
    if (c == 0) continue;
    float ox = (float)x - s_bp[j][0];
    float oy = (float)y - s_bp[j][1];
    float r = s_bp[j][2];
    if (fabsf(ox) <= r && fabsf(oy) <= r) {
      float gg = expf(-(ox * ox + oy * oy) * s_bp[j][3]);
      if (c == 1) a0 = fmaxf(a0, gg);
      else if (c == 2) a1 = fmaxf(a1, gg);
      else a2 = fmaxf(a2, gg);
    }
  }
  int base = HM_OFF + (b * 3 * HWD + y) * HWD + x;
  out[base] = a0;
  out[base + NPX] = a1;
  out[base + 2 * NPX] = a2;
}

extern "C" void kernel_launch(void* const* d_in, const int* in_sizes, int n_in,
                              void* d_out, int out_size, void* d_ws, size_t ws_size,
                              hipStream_t stream) {
  (void)in_sizes; (void)n_in; (void)out_size;
  const float* sf = (const float*)d_in[0];
  const float* gt = (const float*)d_in[1];
  const float* w_shared = (const float*)d_in[2];
  const float* bn_shared = (const float*)d_in[3];
  const float* w1 = (const float*)d_in[4];
  const float* bnH = (const float*)d_in[5];
  const float* w2 = (const float*)d_in[6];
  const float* b2 = (const float*)d_in[7];
  float* out = (float*)d_out;
  char* ws = (char*)d_ws;

  // ws layout (bytes)
  const size_t SH = (size_t)NB * NPX * 64 * 2;          // 18,096,128
  unsigned short* shared_t = (unsigned short*)ws;       // 0
  unsigned short* w1b = (unsigned short*)(ws + SH);                       // 589,824
  unsigned short* w2b = (unsigned short*)(ws + SH + 589824);              // 442,368
  unsigned short* w3b = (unsigned short*)(ws + SH + 589824 + 442368);     // 110,592
  float* boxp = (float*)(ws + SH + 589824 + 442368 + 110592);             // 25,600
  unsigned short* tmp0 = (unsigned short*)(ws + SH + 589824 + 442368 + 110592 + 25600);

  const size_t need_wide = SH + 589824 + 442368 + 110592 + 25600 + 6 * SH;
  const bool wide = ws_size >= need_wide;
  const long long tstride = wide ? (long long)(SH / 2) : 0LL;  // in shorts

  wprep<<<2232, 256, 0, stream>>>(w_shared, w1, w2, w1b, w2b, w3b);
  conv1_mfma<<<dim3(144, NB), 256, 0, stream>>>(sf, w1b, bn_shared, shared_t);

  if (wide) {
    conv_head_mfma<4, 0><<<dim3(144, NB, 6), 256, 0, stream>>>(
        shared_t, w2b, bnH, nullptr, tmp0, nullptr, 0, tstride);
    conv_head_mfma<1, 1><<<dim3(144, NB, 6), 256, 0, stream>>>(
        tmp0, w3b, nullptr, b2, nullptr, out, 0, tstride);
  } else {
    for (int h = 0; h < 6; ++h) {
      conv_head_mfma<4, 0><<<dim3(144, NB), 256, 0, stream>>>(
          shared_t, w2b, bnH, nullptr, tmp0, nullptr, h, 0);
      conv_head_mfma<1, 1><<<dim3(144, NB), 256, 0, stream>>>(
          tmp0, w3b, nullptr, b2, nullptr, out, h, 0);
    }
  }

  targets_kernel<<<(NB * NMAX + 255) / 256, 256, 0, stream>>>(gt, out, boxp);
  heatmap_kernel<<<dim3((NPX + 255) / 256, NB), 256, 0, stream>>>(boxp, out);
}